// Round 1
// baseline (499.692 us; speedup 1.0000x reference)
//
#include <hip/hip_runtime.h>

#define K_DIM 4096
#define N_DIM 4096
#define M_TOT 8192          // B * M = 2 * 4096
#define INT8_BOUND 127.0f

typedef int v4i __attribute__((ext_vector_type(4)));

// ---------------------------------------------------------------------------
// Kernel 1: quantize lhs rows. One block (256 thr) per row of K=4096 floats.
// Writes q_l (int8, [M_TOT x K]) and s_l (fp32 per row).
// ---------------------------------------------------------------------------
__global__ __launch_bounds__(256) void quant_lhs_kernel(const float* __restrict__ lhs,
                                                        char* __restrict__ q_l,
                                                        float* __restrict__ s_l) {
    __shared__ float red[4];
    const int row = blockIdx.x;
    const int t = threadIdx.x;
    const float4* x4 = (const float4*)(lhs + (size_t)row * K_DIM);

    float4 v[4];
    float amax = 0.f;
#pragma unroll
    for (int c = 0; c < 4; ++c) {
        v[c] = x4[t + c * 256];
        amax = fmaxf(amax, fmaxf(fmaxf(fabsf(v[c].x), fabsf(v[c].y)),
                                 fmaxf(fabsf(v[c].z), fabsf(v[c].w))));
    }
#pragma unroll
    for (int off = 32; off > 0; off >>= 1)
        amax = fmaxf(amax, __shfl_xor(amax, off, 64));
    if ((t & 63) == 0) red[t >> 6] = amax;
    __syncthreads();
    amax = fmaxf(fmaxf(red[0], red[1]), fmaxf(red[2], red[3]));

    const float scale = (amax > 0.f) ? (amax / INT8_BOUND) : 1.0f;
    if (t == 0) s_l[row] = scale;

    int* qrow = (int*)(q_l + (size_t)row * K_DIM);
#pragma unroll
    for (int c = 0; c < 4; ++c) {
        int b0 = (int)fminf(127.f, fmaxf(-127.f, rintf(v[c].x / scale)));
        int b1 = (int)fminf(127.f, fmaxf(-127.f, rintf(v[c].y / scale)));
        int b2 = (int)fminf(127.f, fmaxf(-127.f, rintf(v[c].z / scale)));
        int b3 = (int)fminf(127.f, fmaxf(-127.f, rintf(v[c].w / scale)));
        qrow[t + c * 256] = (b0 & 0xff) | ((b1 & 0xff) << 8) | ((b2 & 0xff) << 16) | (b3 << 24);
    }
}

// ---------------------------------------------------------------------------
// Kernel 2: per-column absmax of rhs [K x N]. Grid (N/256, K/128).
// atomicMax on float bits (all non-negative -> uint order == float order).
// ---------------------------------------------------------------------------
__global__ __launch_bounds__(256) void rhs_amax_kernel(const float* __restrict__ rhs,
                                                       unsigned* __restrict__ amax_r) {
    const int n = blockIdx.x * 256 + threadIdx.x;
    const int k0 = blockIdx.y * 128;
    float m = 0.f;
    for (int k = 0; k < 128; ++k)
        m = fmaxf(m, fabsf(rhs[(size_t)(k0 + k) * N_DIM + n]));
    atomicMax(&amax_r[n], __float_as_uint(m));
}

// ---------------------------------------------------------------------------
// Kernel 3: quantize rhs and transpose to q_rT (int8, [N x K], K contiguous)
// via a 64x64 LDS tile. Grid (K/64, N/64).
// ---------------------------------------------------------------------------
__global__ __launch_bounds__(256) void rhs_quant_kernel(const float* __restrict__ rhs,
                                                        const unsigned* __restrict__ amax_r,
                                                        char* __restrict__ q_rt) {
    __shared__ char tile[64 * 80];   // [n][k], padded row stride 80 (16B aligned)
    const int t = threadIdx.x;
    const int k0 = blockIdx.x * 64;
    const int n0 = blockIdx.y * 64;
#pragma unroll
    for (int c = 0; c < 16; ++c) {
        const int lin = c * 256 + t;
        const int kk = lin >> 6;       // 0..63
        const int nn = lin & 63;       // coalesced over n
        const float am = __uint_as_float(amax_r[n0 + nn]);
        const float s = (am > 0.f) ? (am / INT8_BOUND) : 1.f;
        float q = rintf(rhs[(size_t)(k0 + kk) * N_DIM + n0 + nn] / s);
        q = fminf(127.f, fmaxf(-127.f, q));
        tile[nn * 80 + kk] = (char)(int)q;
    }
    __syncthreads();
    const int nn = t >> 2;             // 0..63
    const int kc = (t & 3) * 16;       // 0,16,32,48
    const v4i val = *(const v4i*)&tile[nn * 80 + kc];
    *(v4i*)&q_rt[(size_t)(n0 + nn) * K_DIM + k0 + kc] = val;
}

// ---------------------------------------------------------------------------
// Kernel 4: int8 MFMA GEMM. C[m,n] = sum_k qa[m,k]*qbT[n,k], dequantized.
// 128x128 tile, BK=64, 256 thr = 4 waves in 2x2, each wave 4x4 frags of
// mfma_i32_16x16x64_i8. LDS rows padded to 80B.
// ---------------------------------------------------------------------------
__global__ __launch_bounds__(256) void gemm_i8_kernel(const char* __restrict__ qa,
                                                      const char* __restrict__ qb,
                                                      const float* __restrict__ s_l,
                                                      const unsigned* __restrict__ amax_r,
                                                      float* __restrict__ out) {
    __shared__ char lA[128 * 80];
    __shared__ char lB[128 * 80];
    const int t = threadIdx.x;
    const int lane = t & 63;
    const int wave = t >> 6;
    const int wm = wave >> 1, wn = wave & 1;
    const size_t rowA0 = (size_t)blockIdx.x * 128;
    const size_t rowB0 = (size_t)blockIdx.y * 128;

    v4i acc[4][4];
#pragma unroll
    for (int i = 0; i < 4; ++i)
#pragma unroll
        for (int j = 0; j < 4; ++j)
            acc[i][j] = (v4i){0, 0, 0, 0};

    const int r0 = t >> 2;            // staging row 0..63 (+64 on 2nd chunk)
    const int co = (t & 3) * 16;      // staging byte offset in row
    const int lrow = lane & 15;
    const int lq = lane >> 4;

    for (int k0 = 0; k0 < K_DIM; k0 += 64) {
#pragma unroll
        for (int c = 0; c < 2; ++c) {
            const int r = r0 + c * 64;
            *(v4i*)&lA[r * 80 + co] = *(const v4i*)&qa[(rowA0 + r) * K_DIM + k0 + co];
            *(v4i*)&lB[r * 80 + co] = *(const v4i*)&qb[(rowB0 + r) * K_DIM + k0 + co];
        }
        __syncthreads();

        v4i af[4], bf[4];
#pragma unroll
        for (int i = 0; i < 4; ++i)
            af[i] = *(const v4i*)&lA[(wm * 64 + i * 16 + lrow) * 80 + lq * 16];
#pragma unroll
        for (int j = 0; j < 4; ++j)
            bf[j] = *(const v4i*)&lB[(wn * 64 + j * 16 + lrow) * 80 + lq * 16];

#pragma unroll
        for (int i = 0; i < 4; ++i)
#pragma unroll
            for (int j = 0; j < 4; ++j)
                acc[i][j] = __builtin_amdgcn_mfma_i32_16x16x64_i8(af[i], bf[j], acc[i][j], 0, 0, 0);
        __syncthreads();
    }

    // Epilogue: C/D layout col=lane&15, row=(lane>>4)*4+reg
    const int orow0 = (int)rowA0 + wm * 64 + lq * 4;
    const int ocol0 = (int)rowB0 + wn * 64 + lrow;
#pragma unroll
    for (int i = 0; i < 4; ++i) {
#pragma unroll
        for (int r = 0; r < 4; ++r) {
            const int row = orow0 + i * 16 + r;
            const float sl = s_l[row];
#pragma unroll
            for (int j = 0; j < 4; ++j) {
                const int col = ocol0 + j * 16;
                const float am = __uint_as_float(amax_r[col]);
                const float sr = (am > 0.f) ? (am / INT8_BOUND) : 1.f;
                out[(size_t)row * N_DIM + col] = (float)acc[i][j][r] * sl * sr;
            }
        }
    }
}

// ---------------------------------------------------------------------------
extern "C" void kernel_launch(void* const* d_in, const int* in_sizes, int n_in,
                              void* d_out, int out_size, void* d_ws, size_t ws_size,
                              hipStream_t stream) {
    const float* lhs = (const float*)d_in[0];   // [2,4096,4096] fp32
    const float* rhs = (const float*)d_in[1];   // [4096,4096]  fp32
    float* out = (float*)d_out;                 // [2,4096,4096] fp32

    char* ws = (char*)d_ws;
    char* q_l = ws;                                        // 32 MB
    char* q_rt = ws + (size_t)M_TOT * K_DIM;               // 16 MB
    float* s_l = (float*)(q_rt + (size_t)N_DIM * K_DIM);   // 32 KB
    unsigned* amax_r = (unsigned*)(s_l + M_TOT);           // 16 KB

    hipMemsetAsync(amax_r, 0, N_DIM * sizeof(unsigned), stream);

    quant_lhs_kernel<<<M_TOT, 256, 0, stream>>>(lhs, q_l, s_l);
    rhs_amax_kernel<<<dim3(N_DIM / 256, K_DIM / 128), 256, 0, stream>>>(rhs, amax_r);
    rhs_quant_kernel<<<dim3(K_DIM / 64, N_DIM / 64), 256, 0, stream>>>(rhs, amax_r, q_rt);
    gemm_i8_kernel<<<dim3(M_TOT / 128, N_DIM / 128), 256, 0, stream>>>(q_l, q_rt, s_l, amax_r, out);
}

// Round 2
// 428.487 us; speedup vs baseline: 1.1662x; 1.1662x over previous
//
#include <hip/hip_runtime.h>

#define K_DIM 4096
#define N_DIM 4096
#define M_TOT 8192          // B * M = 2 * 4096
#define INT8_BOUND 127.0f
#define BK 128              // k-bytes per GEMM LDS tile (full cacheline rows)

typedef int v4i  __attribute__((ext_vector_type(4)));
typedef int v16i __attribute__((ext_vector_type(16)));

// async global->LDS, 16B per lane; dest = wave-uniform base + lane*16
#define GLOAD_LDS16(g, l)                                                      \
    __builtin_amdgcn_global_load_lds(                                          \
        (const __attribute__((address_space(1))) void*)(g),                    \
        (__attribute__((address_space(3))) void*)(l), 16, 0, 0)

// ---------------------------------------------------------------------------
// Kernel 1: quantize lhs rows. One block (256 thr) per row of K=4096 floats.
// ---------------------------------------------------------------------------
__global__ __launch_bounds__(256) void quant_lhs_kernel(const float* __restrict__ lhs,
                                                        char* __restrict__ q_l,
                                                        float* __restrict__ s_l) {
    __shared__ float red[4];
    const int row = blockIdx.x;
    const int t = threadIdx.x;
    const float4* x4 = (const float4*)(lhs + (size_t)row * K_DIM);

    float4 v[4];
    float amax = 0.f;
#pragma unroll
    for (int c = 0; c < 4; ++c) {
        v[c] = x4[t + c * 256];
        amax = fmaxf(amax, fmaxf(fmaxf(fabsf(v[c].x), fabsf(v[c].y)),
                                 fmaxf(fabsf(v[c].z), fabsf(v[c].w))));
    }
#pragma unroll
    for (int off = 32; off > 0; off >>= 1)
        amax = fmaxf(amax, __shfl_xor(amax, off, 64));
    if ((t & 63) == 0) red[t >> 6] = amax;
    __syncthreads();
    amax = fmaxf(fmaxf(red[0], red[1]), fmaxf(red[2], red[3]));

    const float scale = (amax > 0.f) ? (amax / INT8_BOUND) : 1.0f;
    if (t == 0) s_l[row] = scale;

    int* qrow = (int*)(q_l + (size_t)row * K_DIM);
#pragma unroll
    for (int c = 0; c < 4; ++c) {
        int b0 = (int)fminf(127.f, fmaxf(-127.f, rintf(v[c].x / scale)));
        int b1 = (int)fminf(127.f, fmaxf(-127.f, rintf(v[c].y / scale)));
        int b2 = (int)fminf(127.f, fmaxf(-127.f, rintf(v[c].z / scale)));
        int b3 = (int)fminf(127.f, fmaxf(-127.f, rintf(v[c].w / scale)));
        qrow[t + c * 256] = (b0 & 0xff) | ((b1 & 0xff) << 8) | ((b2 & 0xff) << 16) | (b3 << 24);
    }
}

// ---------------------------------------------------------------------------
// Kernel 2: per-column absmax of rhs [K x N]. float4 cols, 8 outstanding loads.
// Grid (N/1024, K/64) = (4, 64).
// ---------------------------------------------------------------------------
__global__ __launch_bounds__(256) void rhs_amax_kernel(const float* __restrict__ rhs,
                                                       unsigned* __restrict__ amax_r) {
    const int t = threadIdx.x;
    const int nf = blockIdx.x * 256 + t;       // float4 column group 0..1023
    const int k0 = blockIdx.y * 64;
    const float4* r4 = (const float4*)rhs;
    float4 m = {0.f, 0.f, 0.f, 0.f};
#pragma unroll 8
    for (int k = 0; k < 64; ++k) {
        float4 v = r4[(size_t)(k0 + k) * (N_DIM / 4) + nf];
        m.x = fmaxf(m.x, fabsf(v.x));
        m.y = fmaxf(m.y, fabsf(v.y));
        m.z = fmaxf(m.z, fabsf(v.z));
        m.w = fmaxf(m.w, fabsf(v.w));
    }
    atomicMax(&amax_r[nf * 4 + 0], __float_as_uint(m.x));
    atomicMax(&amax_r[nf * 4 + 1], __float_as_uint(m.y));
    atomicMax(&amax_r[nf * 4 + 2], __float_as_uint(m.z));
    atomicMax(&amax_r[nf * 4 + 3], __float_as_uint(m.w));
}

// ---------------------------------------------------------------------------
// Kernel 3: quantize rhs and transpose to q_rT (int8, [N x K], K contiguous).
// k-tile 128 (full 128B output lines), n-tile 64. Grid (K/128, N/64).
// ---------------------------------------------------------------------------
__global__ __launch_bounds__(256) void rhs_quant_kernel(const float* __restrict__ rhs,
                                                        const unsigned* __restrict__ amax_r,
                                                        char* __restrict__ q_rt) {
    __shared__ char tile[64 * 144];   // [n][k], stride 144 (16B-aligned, bank-shifted)
    const int t = threadIdx.x;
    const int k0 = blockIdx.x * 128;
    const int n0 = blockIdx.y * 64;
    const int nf = t & 15;            // my float4 column group (constant per thread)

    float s[4];
#pragma unroll
    for (int q = 0; q < 4; ++q) {
        float am = __uint_as_float(amax_r[n0 + nf * 4 + q]);
        s[q] = (am > 0.f) ? (am / INT8_BOUND) : 1.f;
    }
    const float4* r4 = (const float4*)rhs;
#pragma unroll
    for (int c = 0; c < 8; ++c) {
        const int kk = c * 16 + (t >> 4);
        float4 v = r4[(size_t)(k0 + kk) * (N_DIM / 4) + (n0 >> 2) + nf];
        tile[(nf * 4 + 0) * 144 + kk] = (char)(int)fminf(127.f, fmaxf(-127.f, rintf(v.x / s[0])));
        tile[(nf * 4 + 1) * 144 + kk] = (char)(int)fminf(127.f, fmaxf(-127.f, rintf(v.y / s[1])));
        tile[(nf * 4 + 2) * 144 + kk] = (char)(int)fminf(127.f, fmaxf(-127.f, rintf(v.z / s[2])));
        tile[(nf * 4 + 3) * 144 + kk] = (char)(int)fminf(127.f, fmaxf(-127.f, rintf(v.w / s[3])));
    }
    __syncthreads();
#pragma unroll
    for (int c = 0; c < 2; ++c) {
        const int idx = c * 256 + t;
        const int row = idx >> 3;          // 0..63
        const int ch = (idx & 7) * 16;     // 0..112
        *(v4i*)&q_rt[(size_t)(n0 + row) * K_DIM + k0 + ch] = *(const v4i*)&tile[row * 144 + ch];
    }
}

// ---------------------------------------------------------------------------
// Kernel 4: int8 MFMA GEMM, 128x128 tile, BK=128, global_load_lds staging,
// XOR-swizzled LDS (chunk slot = c ^ (r&7)), mfma_i32_32x32x32_i8.
// 4 waves 2x2, each wave 64x64 = 2x2 frags of 32x32.
// ---------------------------------------------------------------------------
__global__ __launch_bounds__(256) void gemm_i8_kernel(const char* __restrict__ qa,
                                                      const char* __restrict__ qb,
                                                      const float* __restrict__ s_l,
                                                      const unsigned* __restrict__ amax_r,
                                                      float* __restrict__ out) {
    __shared__ char lA[128 * BK];   // 16 KB, swizzled
    __shared__ char lB[128 * BK];
    const int t = threadIdx.x;
    const int lane = t & 63;
    const int ln31 = lane & 31;
    const int lhi = lane >> 5;
    const int wave = t >> 6;
    const int wm = wave >> 1, wn = wave & 1;
    const size_t rowA0 = (size_t)blockIdx.x * 128;
    const size_t rowB0 = (size_t)blockIdx.y * 128;

    v16i acc[2][2];
#pragma unroll
    for (int i = 0; i < 2; ++i)
#pragma unroll
        for (int j = 0; j < 2; ++j)
            acc[i][j] = (v16i)(0);

    // staging assignment: slot s = g*256 + t; r = s>>3, lds slot cs = s&7,
    // fetch global chunk cg = cs ^ (r&7). Per-wave lds dest = base + lane*16.
    int sr_[4], sc_[4];
#pragma unroll
    for (int g = 0; g < 4; ++g) {
        const int s = g * 256 + t;
        sr_[g] = s >> 3;
        sc_[g] = (s & 7) ^ (sr_[g] & 7);
    }

    for (int k0 = 0; k0 < K_DIM; k0 += BK) {
#pragma unroll
        for (int g = 0; g < 4; ++g) {
            const int s = g * 256 + t;
            GLOAD_LDS16(qa + (rowA0 + sr_[g]) * K_DIM + k0 + sc_[g] * 16, &lA[s * 16]);
            GLOAD_LDS16(qb + (rowB0 + sr_[g]) * K_DIM + k0 + sc_[g] * 16, &lB[s * 16]);
        }
        __syncthreads();

#pragma unroll
        for (int ks = 0; ks < BK; ks += 32) {
            const int c = (ks >> 4) + lhi;
            v4i af[2], bf[2];
#pragma unroll
            for (int i = 0; i < 2; ++i) {
                const int r = wm * 64 + i * 32 + ln31;
                af[i] = *(const v4i*)&lA[r * BK + ((c ^ (r & 7)) << 4)];
            }
#pragma unroll
            for (int j = 0; j < 2; ++j) {
                const int r = wn * 64 + j * 32 + ln31;
                bf[j] = *(const v4i*)&lB[r * BK + ((c ^ (r & 7)) << 4)];
            }
#pragma unroll
            for (int i = 0; i < 2; ++i)
#pragma unroll
                for (int j = 0; j < 2; ++j)
                    acc[i][j] = __builtin_amdgcn_mfma_i32_32x32x32_i8(af[i], bf[j], acc[i][j], 0, 0, 0);
        }
        __syncthreads();
    }

    // Epilogue: 32x32 C/D layout: col=lane&31, row=(reg&3)+8*(reg>>2)+4*(lane>>5)
#pragma unroll
    for (int i = 0; i < 2; ++i) {
        const int rbase = (int)rowA0 + wm * 64 + i * 32 + 4 * lhi;
        float sl[16];
#pragma unroll
        for (int reg = 0; reg < 16; ++reg)
            sl[reg] = s_l[rbase + (reg & 3) + 8 * (reg >> 2)];
#pragma unroll
        for (int j = 0; j < 2; ++j) {
            const int col = (int)rowB0 + wn * 64 + j * 32 + ln31;
            const float am = __uint_as_float(amax_r[col]);
            const float sr = (am > 0.f) ? (am / INT8_BOUND) : 1.f;
            const v16i a = acc[i][j];
#pragma unroll
            for (int reg = 0; reg < 16; ++reg) {
                const int row = rbase + (reg & 3) + 8 * (reg >> 2);
                out[(size_t)row * N_DIM + col] = (float)a[reg] * sl[reg] * sr;
            }
        }
    }
}

// ---------------------------------------------------------------------------
extern "C" void kernel_launch(void* const* d_in, const int* in_sizes, int n_in,
                              void* d_out, int out_size, void* d_ws, size_t ws_size,
                              hipStream_t stream) {
    const float* lhs = (const float*)d_in[0];   // [2,4096,4096] fp32
    const float* rhs = (const float*)d_in[1];   // [4096,4096]  fp32
    float* out = (float*)d_out;                 // [2,4096,4096] fp32

    char* ws = (char*)d_ws;
    char* q_l = ws;                                        // 32 MB
    char* q_rt = ws + (size_t)M_TOT * K_DIM;               // 16 MB
    float* s_l = (float*)(q_rt + (size_t)N_DIM * K_DIM);   // 32 KB
    unsigned* amax_r = (unsigned*)(s_l + M_TOT);           // 16 KB

    hipMemsetAsync(amax_r, 0, N_DIM * sizeof(unsigned), stream);

    quant_lhs_kernel<<<M_TOT, 256, 0, stream>>>(lhs, q_l, s_l);
    rhs_amax_kernel<<<dim3(N_DIM / 1024, K_DIM / 64), 256, 0, stream>>>(rhs, amax_r);
    rhs_quant_kernel<<<dim3(K_DIM / 128, N_DIM / 64), 256, 0, stream>>>(rhs, amax_r, q_rt);
    gemm_i8_kernel<<<dim3(M_TOT / 128, N_DIM / 128), 256, 0, stream>>>(q_l, q_rt, s_l, amax_r, out);
}

// Round 3
// 425.714 us; speedup vs baseline: 1.1738x; 1.0065x over previous
//
#include <hip/hip_runtime.h>

#define K_DIM 4096
#define N_DIM 4096
#define M_TOT 8192          // B * M = 2 * 4096
#define INT8_BOUND 127.0f
#define BK 128              // k-bytes per GEMM LDS tile (full cacheline rows)

typedef int v4i  __attribute__((ext_vector_type(4)));
typedef int v16i __attribute__((ext_vector_type(16)));

// async global->LDS, 16B per lane; dest = wave-uniform base + lane*16
#define GLOAD_LDS16(g, l)                                                      \
    __builtin_amdgcn_global_load_lds(                                          \
        (const __attribute__((address_space(1))) void*)(g),                    \
        (__attribute__((address_space(3))) void*)(l), 16, 0, 0)

__device__ __forceinline__ int sat8(float x) {
    return (int)fminf(127.f, fmaxf(-127.f, x));
}

// ---------------------------------------------------------------------------
// Kernel 1: quantize lhs rows. One block (256 thr) per row of K=4096 floats.
// One fdiv per thread (scale), per-element multiply by reciprocal.
// ---------------------------------------------------------------------------
__global__ __launch_bounds__(256) void quant_lhs_kernel(const float* __restrict__ lhs,
                                                        char* __restrict__ q_l,
                                                        float* __restrict__ s_l) {
    __shared__ float red[4];
    const int row = blockIdx.x;
    const int t = threadIdx.x;
    const float4* x4 = (const float4*)(lhs + (size_t)row * K_DIM);

    float4 v[4];
    float amax = 0.f;
#pragma unroll
    for (int c = 0; c < 4; ++c) {
        v[c] = x4[t + c * 256];
        amax = fmaxf(amax, fmaxf(fmaxf(fabsf(v[c].x), fabsf(v[c].y)),
                                 fmaxf(fabsf(v[c].z), fabsf(v[c].w))));
    }
#pragma unroll
    for (int off = 32; off > 0; off >>= 1)
        amax = fmaxf(amax, __shfl_xor(amax, off, 64));
    if ((t & 63) == 0) red[t >> 6] = amax;
    __syncthreads();
    amax = fmaxf(fmaxf(red[0], red[1]), fmaxf(red[2], red[3]));

    const float scale = (amax > 0.f) ? (amax / INT8_BOUND) : 1.0f;
    const float inv = (amax > 0.f) ? (INT8_BOUND / amax) : 1.0f;
    if (t == 0) s_l[row] = scale;

    int* qrow = (int*)(q_l + (size_t)row * K_DIM);
#pragma unroll
    for (int c = 0; c < 4; ++c) {
        int b0 = sat8(rintf(v[c].x * inv));
        int b1 = sat8(rintf(v[c].y * inv));
        int b2 = sat8(rintf(v[c].z * inv));
        int b3 = sat8(rintf(v[c].w * inv));
        qrow[t + c * 256] = (b0 & 0xff) | ((b1 & 0xff) << 8) | ((b2 & 0xff) << 16) | (b3 << 24);
    }
}

// ---------------------------------------------------------------------------
// Kernel 2: per-column absmax of rhs [K x N]. float4 cols, 8 outstanding loads.
// Grid (N/1024, K/64) = (4, 64).
// ---------------------------------------------------------------------------
__global__ __launch_bounds__(256) void rhs_amax_kernel(const float* __restrict__ rhs,
                                                       unsigned* __restrict__ amax_r) {
    const int t = threadIdx.x;
    const int nf = blockIdx.x * 256 + t;       // float4 column group 0..1023
    const int k0 = blockIdx.y * 64;
    const float4* r4 = (const float4*)rhs;
    float4 m = {0.f, 0.f, 0.f, 0.f};
#pragma unroll 8
    for (int k = 0; k < 64; ++k) {
        float4 v = r4[(size_t)(k0 + k) * (N_DIM / 4) + nf];
        m.x = fmaxf(m.x, fabsf(v.x));
        m.y = fmaxf(m.y, fabsf(v.y));
        m.z = fmaxf(m.z, fabsf(v.z));
        m.w = fmaxf(m.w, fabsf(v.w));
    }
    atomicMax(&amax_r[nf * 4 + 0], __float_as_uint(m.x));
    atomicMax(&amax_r[nf * 4 + 1], __float_as_uint(m.y));
    atomicMax(&amax_r[nf * 4 + 2], __float_as_uint(m.z));
    atomicMax(&amax_r[nf * 4 + 3], __float_as_uint(m.w));
}

// ---------------------------------------------------------------------------
// Kernel 3: quantize rhs and transpose to q_rT (int8, [N x K], K contiguous).
// k-tile 128, n-tile 64. Grid (K/128, N/64). Each thread owns 4 n-rows x 8
// contiguous k's -> packs to int2 -> 4 ds_write_b64 (vs 32 byte-stores).
// ---------------------------------------------------------------------------
__global__ __launch_bounds__(256) void rhs_quant_kernel(const float* __restrict__ rhs,
                                                        const unsigned* __restrict__ amax_r,
                                                        char* __restrict__ q_rt) {
    __shared__ char tile[64 * 136];   // [n][k], stride 136 (8B-aligned, bank-shifted)
    const int t = threadIdx.x;
    const int k0 = blockIdx.x * 128;
    const int n0 = blockIdx.y * 64;
    const int nf = t & 15;            // float4 column group
    const int kb = (t >> 4) * 8;      // contiguous 8-k strip

    float inv[4];
#pragma unroll
    for (int q = 0; q < 4; ++q) {
        float am = __uint_as_float(amax_r[n0 + nf * 4 + q]);
        inv[q] = (am > 0.f) ? (INT8_BOUND / am) : 1.f;
    }
    const float4* r4 = (const float4*)rhs;
    int vals[4][8];
#pragma unroll
    for (int c = 0; c < 8; ++c) {
        float4 v = r4[(size_t)(k0 + kb + c) * (N_DIM / 4) + (n0 >> 2) + nf];
        vals[0][c] = sat8(rintf(v.x * inv[0]));
        vals[1][c] = sat8(rintf(v.y * inv[1]));
        vals[2][c] = sat8(rintf(v.z * inv[2]));
        vals[3][c] = sat8(rintf(v.w * inv[3]));
    }
#pragma unroll
    for (int q = 0; q < 4; ++q) {
        int2 p;
        p.x = (vals[q][0] & 0xff) | ((vals[q][1] & 0xff) << 8) |
              ((vals[q][2] & 0xff) << 16) | (vals[q][3] << 24);
        p.y = (vals[q][4] & 0xff) | ((vals[q][5] & 0xff) << 8) |
              ((vals[q][6] & 0xff) << 16) | (vals[q][7] << 24);
        *(int2*)&tile[(nf * 4 + q) * 136 + kb] = p;
    }
    __syncthreads();
#pragma unroll
    for (int c = 0; c < 2; ++c) {
        const int idx = c * 256 + t;
        const int row = idx >> 3;          // 0..63
        const int ch = (idx & 7) * 16;     // 0..112
        *(v4i*)&q_rt[(size_t)(n0 + row) * K_DIM + k0 + ch] = *(const v4i*)&tile[row * 136 + ch];
    }
}

// ---------------------------------------------------------------------------
// Kernel 4: int8 MFMA GEMM, 128x128 tile, BK=128, global_load_lds staging,
// XOR-swizzled LDS (chunk slot = c ^ (r&7)), mfma_i32_32x32x32_i8.
// __launch_bounds__(256,4): cap unified VGPR+AGPR at 128 -> 4 blocks/CU
// (was 3 at 160 regs) for more wave-level overlap of the barrier drain.
// ---------------------------------------------------------------------------
__global__ __launch_bounds__(256, 4) void gemm_i8_kernel(const char* __restrict__ qa,
                                                         const char* __restrict__ qb,
                                                         const float* __restrict__ s_l,
                                                         const unsigned* __restrict__ amax_r,
                                                         float* __restrict__ out) {
    __shared__ char lA[128 * BK];   // 16 KB, swizzled
    __shared__ char lB[128 * BK];
    const int t = threadIdx.x;
    const int lane = t & 63;
    const int ln31 = lane & 31;
    const int lhi = lane >> 5;
    const int wave = t >> 6;
    const int wm = wave >> 1, wn = wave & 1;
    const size_t rowA0 = (size_t)blockIdx.x * 128;
    const size_t rowB0 = (size_t)blockIdx.y * 128;

    v16i acc[2][2];
#pragma unroll
    for (int i = 0; i < 2; ++i)
#pragma unroll
        for (int j = 0; j < 2; ++j)
            acc[i][j] = (v16i)(0);

    // staging: slot s = g*256 + t; row r = s>>3, lds chunk-slot cs = s&7,
    // global chunk cg = cs ^ (r&7). Same offset table serves A and B.
    int goff[4];
#pragma unroll
    for (int g = 0; g < 4; ++g) {
        const int s = g * 256 + t;
        const int r = s >> 3;
        const int cg = (s & 7) ^ (r & 7);
        goff[g] = r * K_DIM + cg * 16;
    }
    const char* baseA = qa + rowA0 * K_DIM;
    const char* baseB = qb + rowB0 * K_DIM;

    for (int k0 = 0; k0 < K_DIM; k0 += BK) {
#pragma unroll
        for (int g = 0; g < 4; ++g) {
            const int s = g * 256 + t;
            GLOAD_LDS16(baseA + k0 + goff[g], &lA[s * 16]);
            GLOAD_LDS16(baseB + k0 + goff[g], &lB[s * 16]);
        }
        __syncthreads();

#pragma unroll
        for (int ks = 0; ks < BK; ks += 32) {
            const int c = (ks >> 4) + lhi;
            v4i af[2], bf[2];
#pragma unroll
            for (int i = 0; i < 2; ++i) {
                const int r = wm * 64 + i * 32 + ln31;
                af[i] = *(const v4i*)&lA[r * BK + ((c ^ (r & 7)) << 4)];
            }
#pragma unroll
            for (int j = 0; j < 2; ++j) {
                const int r = wn * 64 + j * 32 + ln31;
                bf[j] = *(const v4i*)&lB[r * BK + ((c ^ (r & 7)) << 4)];
            }
#pragma unroll
            for (int i = 0; i < 2; ++i)
#pragma unroll
                for (int j = 0; j < 2; ++j)
                    acc[i][j] = __builtin_amdgcn_mfma_i32_32x32x32_i8(af[i], bf[j], acc[i][j], 0, 0, 0);
        }
        __syncthreads();
    }

    // Epilogue: 32x32 C/D layout: col=lane&31, row=(reg&3)+8*(reg>>2)+4*(lane>>5)
#pragma unroll
    for (int i = 0; i < 2; ++i) {
        const int rbase = (int)rowA0 + wm * 64 + i * 32 + 4 * lhi;
#pragma unroll
        for (int j = 0; j < 2; ++j) {
            const int col = (int)rowB0 + wn * 64 + j * 32 + ln31;
            const float am = __uint_as_float(amax_r[col]);
            const float sr = (am > 0.f) ? (am / INT8_BOUND) : 1.f;
            const v16i a = acc[i][j];
#pragma unroll
            for (int reg = 0; reg < 16; ++reg) {
                const int row = rbase + (reg & 3) + 8 * (reg >> 2);
                out[(size_t)row * N_DIM + col] = (float)a[reg] * s_l[row] * sr;
            }
        }
    }
}

// ---------------------------------------------------------------------------
extern "C" void kernel_launch(void* const* d_in, const int* in_sizes, int n_in,
                              void* d_out, int out_size, void* d_ws, size_t ws_size,
                              hipStream_t stream) {
    const float* lhs = (const float*)d_in[0];   // [2,4096,4096] fp32
    const float* rhs = (const float*)d_in[1];   // [4096,4096]  fp32
    float* out = (float*)d_out;                 // [2,4096,4096] fp32

    char* ws = (char*)d_ws;
    char* q_l = ws;                                        // 32 MB
    char* q_rt = ws + (size_t)M_TOT * K_DIM;               // 16 MB
    float* s_l = (float*)(q_rt + (size_t)N_DIM * K_DIM);   // 32 KB
    unsigned* amax_r = (unsigned*)(s_l + M_TOT);           // 16 KB

    hipMemsetAsync(amax_r, 0, N_DIM * sizeof(unsigned), stream);

    quant_lhs_kernel<<<M_TOT, 256, 0, stream>>>(lhs, q_l, s_l);
    rhs_amax_kernel<<<dim3(N_DIM / 1024, K_DIM / 64), 256, 0, stream>>>(rhs, amax_r);
    rhs_quant_kernel<<<dim3(K_DIM / 128, N_DIM / 64), 256, 0, stream>>>(rhs, amax_r, q_rt);
    gemm_i8_kernel<<<dim3(M_TOT / 128, N_DIM / 128), 256, 0, stream>>>(q_l, q_rt, s_l, amax_r, out);
}